// Round 2
// baseline (129.779 us; speedup 1.0000x reference)
//
#include <hip/hip_runtime.h>
#include <hip/hip_bf16.h>

#define NTOT   8192
#define BHALF  4096
#define DDIM   256
#define TEMP_INV 10.0f
#define BM     128
#define BN     64
#define CSPLIT 8
#define LDSTRIDE 280   // 256 + 24 pad (keeps 16B alignment, 2-way-only bank aliasing)

typedef __attribute__((ext_vector_type(8))) short bf16x8_t;  // 8 bf16 in 4 VGPRs
typedef __attribute__((ext_vector_type(4))) float f32x4_t;   // MFMA C/D

__device__ inline unsigned short f2bf(float x) {
    __hip_bfloat16 h = __float2bfloat16(x);
    return __builtin_bit_cast(unsigned short, h);
}
__device__ inline float bf2f(unsigned short u) {
    return __bfloat162float(__builtin_bit_cast(__hip_bfloat16, u));
}

// ---- kernel 1: row-normalize (fp32) and cast to bf16. One wave per row. ----
__global__ void norm_cast_kernel(const float* __restrict__ zi,
                                 const float* __restrict__ zj,
                                 unsigned short* __restrict__ zn) {
    int gtid = blockIdx.x * blockDim.x + threadIdx.x;
    int row  = gtid >> 6;
    int lane = gtid & 63;
    const float* src = (row < BHALF) ? (zi + (size_t)row * DDIM)
                                     : (zj + (size_t)(row - BHALF) * DDIM);
    float4 v = reinterpret_cast<const float4*>(src)[lane];
    float ss = v.x*v.x + v.y*v.y + v.z*v.z + v.w*v.w;
    #pragma unroll
    for (int off = 32; off >= 1; off >>= 1) ss += __shfl_xor(ss, off);
    float scale = 1.0f / fmaxf(sqrtf(ss), 1e-8f);
    ushort4 o;
    o.x = f2bf(v.x * scale);
    o.y = f2bf(v.y * scale);
    o.z = f2bf(v.z * scale);
    o.w = f2bf(v.w * scale);
    reinterpret_cast<ushort4*>(zn + (size_t)row * DDIM)[lane] = o;
}

// ---- kernel 2: positive-pair logit: posdot[k] = dot(zn[k], zn[k+B]) / temp ----
__global__ void posdot_kernel(const unsigned short* __restrict__ zn,
                              float* __restrict__ posdot) {
    int gtid = blockIdx.x * blockDim.x + threadIdx.x;
    int k    = gtid >> 6;
    int lane = gtid & 63;
    ushort4 ua = reinterpret_cast<const ushort4*>(zn + (size_t)k * DDIM)[lane];
    ushort4 ub = reinterpret_cast<const ushort4*>(zn + (size_t)(k + BHALF) * DDIM)[lane];
    float s = bf2f(ua.x)*bf2f(ub.x) + bf2f(ua.y)*bf2f(ub.y)
            + bf2f(ua.z)*bf2f(ub.z) + bf2f(ua.w)*bf2f(ub.w);
    #pragma unroll
    for (int off = 32; off >= 1; off >>= 1) s += __shfl_xor(s, off);
    if (lane == 0) posdot[k] = s * TEMP_INV;
}

// ---- kernel 3: fused sim-GEMM + row-wise sum of exp(logit), diag masked ----
// grid (NTOT/BM, CSPLIT), 256 threads = 4 waves. Wave w owns rows R0+w*32..+31.
// A frags in registers; B tile (64 cols x 256 K) staged in padded LDS.
__global__ void __launch_bounds__(256)
gemm_expsum_kernel(const unsigned short* __restrict__ zn,
                   float* __restrict__ s_arr) {
    __shared__ unsigned short ldsB[64 * LDSTRIDE];   // 35840 B
    const int tid  = threadIdx.x;
    const int lane = tid & 63;
    const int wv   = tid >> 6;        // 0..3
    const int m    = lane & 15;       // A-operand row / B-operand col / C col
    const int quad = lane >> 4;       // 0..3
    const int R0   = blockIdx.x * BM;
    const int CB   = blockIdx.y * (NTOT / CSPLIT);   // 1024-col slice

    // A fragments: rows R0 + wv*32 + rf*16 + m, k = kk*32 + quad*8 + j
    bf16x8_t afrag[2][8];
    #pragma unroll
    for (int rf = 0; rf < 2; ++rf) {
        const unsigned short* arow = zn + (size_t)(R0 + wv*32 + rf*16 + m) * DDIM;
        #pragma unroll
        for (int kk = 0; kk < 8; ++kk)
            afrag[rf][kk] = *reinterpret_cast<const bf16x8_t*>(arow + kk*32 + quad*8);
    }

    float expacc[2][4] = {{0.f,0.f,0.f,0.f},{0.f,0.f,0.f,0.f}};

    for (int it = 0; it < (NTOT / CSPLIT) / BN; ++it) {   // 16 iters
        const int C0 = CB + it * BN;
        __syncthreads();   // protect LDS from previous iter's readers
        // stage B tile: 64 rows x 256 bf16 = 2048 16B-chunks over 256 threads
        #pragma unroll
        for (int s = 0; s < 8; ++s) {
            int ci = s * 256 + tid;
            int n = ci >> 5, c = ci & 31;     // 32 chunks of 8 bf16 per 256-elem row
            bf16x8_t v = *reinterpret_cast<const bf16x8_t*>(zn + (size_t)(C0 + n) * DDIM + c * 8);
            *reinterpret_cast<bf16x8_t*>(&ldsB[n * LDSTRIDE + c * 8]) = v;
        }
        __syncthreads();

        f32x4_t cacc[2][4];
        #pragma unroll
        for (int rf = 0; rf < 2; ++rf)
            #pragma unroll
            for (int cf = 0; cf < 4; ++cf)
                cacc[rf][cf] = (f32x4_t){0.f, 0.f, 0.f, 0.f};

        #pragma unroll
        for (int kk = 0; kk < 8; ++kk) {
            bf16x8_t b[4];
            #pragma unroll
            for (int cf = 0; cf < 4; ++cf)
                b[cf] = *reinterpret_cast<const bf16x8_t*>(
                            &ldsB[(cf*16 + m) * LDSTRIDE + kk*32 + quad*8]);
            #pragma unroll
            for (int cf = 0; cf < 4; ++cf)
                #pragma unroll
                for (int rf = 0; rf < 2; ++rf)
                    cacc[rf][cf] = __builtin_amdgcn_mfma_f32_16x16x32_bf16(
                        afrag[rf][kk], b[cf], cacc[rf][cf], 0, 0, 0);
        }

        // epilogue: exp and accumulate per row; mask j==k
        #pragma unroll
        for (int rf = 0; rf < 2; ++rf) {
            #pragma unroll
            for (int cf = 0; cf < 4; ++cf) {
                int gc = C0 + cf*16 + m;
                #pragma unroll
                for (int r = 0; r < 4; ++r) {
                    int gr = R0 + wv*32 + rf*16 + quad*4 + r;
                    float e = __expf(cacc[rf][cf][r] * TEMP_INV);
                    expacc[rf][r] += (gr == gc) ? 0.0f : e;
                }
            }
        }
    }

    // reduce over the 16 lanes (m) that share a row, then one atomic per row
    #pragma unroll
    for (int rf = 0; rf < 2; ++rf)
        #pragma unroll
        for (int r = 0; r < 4; ++r) {
            float v = expacc[rf][r];
            v += __shfl_xor(v, 1);
            v += __shfl_xor(v, 2);
            v += __shfl_xor(v, 4);
            v += __shfl_xor(v, 8);
            if (m == 0)
                atomicAdd(&s_arr[R0 + wv*32 + rf*16 + quad*4 + r], v);
        }
}

// ---- kernel 4: loss_k = log(s_k) - posdot[k%B]; masked mean -> scalar ----
__global__ void finalize_kernel(const float* __restrict__ s_arr,
                                const float* __restrict__ posdot,
                                const unsigned char* __restrict__ mask,
                                float* __restrict__ out) {
    int tid = threadIdx.x, lane = tid & 63, wv = tid >> 6;
    float tot = 0.f, cnt = 0.f;
    for (int k = tid; k < NTOT; k += 256) {
        int kb = k & (BHALF - 1);
        if (mask[kb] != 0) {
            tot += logf(s_arr[k]) - posdot[kb];
            cnt += 1.f;
        }
    }
    #pragma unroll
    for (int off = 32; off >= 1; off >>= 1) {
        tot += __shfl_xor(tot, off);
        cnt += __shfl_xor(cnt, off);
    }
    __shared__ float st[4], sc[4];
    if (lane == 0) { st[wv] = tot; sc[wv] = cnt; }
    __syncthreads();
    if (tid == 0) {
        float T = st[0] + st[1] + st[2] + st[3];
        float C = sc[0] + sc[1] + sc[2] + sc[3];
        out[0] = (C > 0.f) ? (T / fmaxf(C, 1.f)) : 0.f;
    }
}

extern "C" void kernel_launch(void* const* d_in, const int* in_sizes, int n_in,
                              void* d_out, int out_size, void* d_ws, size_t ws_size,
                              hipStream_t stream) {
    const float* zi = (const float*)d_in[0];
    const float* zj = (const float*)d_in[1];
    const unsigned char* mask = (const unsigned char*)d_in[2];
    float* out = (float*)d_out;

    // ws layout: [0, 4MB) zn bf16 (8192x256); then s_arr[8192] f32; posdot[4096] f32
    unsigned short* zn = (unsigned short*)d_ws;
    float* s_arr  = (float*)((char*)d_ws + (size_t)NTOT * DDIM * 2);
    float* posdot = s_arr + NTOT;

    hipMemsetAsync(s_arr, 0, NTOT * sizeof(float), stream);
    norm_cast_kernel<<<dim3(NTOT / 4), dim3(256), 0, stream>>>(zi, zj, zn);
    posdot_kernel<<<dim3(BHALF / 4), dim3(256), 0, stream>>>(zn, posdot);
    gemm_expsum_kernel<<<dim3(NTOT / BM, CSPLIT), dim3(256), 0, stream>>>(zn, s_arr);
    finalize_kernel<<<dim3(1), dim3(256), 0, stream>>>(s_arr, posdot, mask, out);
}